// Round 1
// baseline (1125.128 us; speedup 1.0000x reference)
//
#include <hip/hip_runtime.h>

#define NB 10   // labels 1..10
#define BATCH 8
#define EPSF 1e-6f

constexpr int ELEMS_PER_BATCH = 128 * 128 * 128;        // 2,097,152
constexpr int VEC_PER_BATCH   = ELEMS_PER_BATCH / 4;    // 524,288 float4
constexpr int THREADS         = 256;
constexpr int VPT             = 8;                      // float4 loads per thread
constexpr int BLOCKS_PER_BATCH = VEC_PER_BATCH / (THREADS * VPT); // 256

// ws layout (floats): accI[BATCH][NB], accX[BATCH][NB], accT[BATCH][NB], accC[NB]
constexpr int WS_FLOATS = 3 * BATCH * NB + NB;

__global__ __launch_bounds__(THREADS)
void dice_partial(const float* __restrict__ x,
                  const float* __restrict__ t,
                  const int*   __restrict__ s,
                  float* __restrict__ acc)
{
    const int batch = blockIdx.y;
    const long long base = (long long)batch * VEC_PER_BATCH
                         + (long long)blockIdx.x * (THREADS * VPT);
    const float4* x4 = reinterpret_cast<const float4*>(x) + base;
    const float4* t4 = reinterpret_cast<const float4*>(t) + base;
    const int4*   s4 = reinterpret_cast<const int4*>(s)   + base;

    float aI[NB], aX[NB], aT[NB], aC[NB];
#pragma unroll
    for (int k = 0; k < NB; ++k) { aI[k] = 0.f; aX[k] = 0.f; aT[k] = 0.f; aC[k] = 0.f; }

#pragma unroll
    for (int i = 0; i < VPT; ++i) {
        const int idx = i * THREADS + threadIdx.x;   // coalesced: lane-contiguous
        const float4 xv = x4[idx];
        const float4 tv = t4[idx];
        const int4   sv = s4[idx];
        const float xs[4] = { xv.x, xv.y, xv.z, xv.w };
        const float ts[4] = { tv.x, tv.y, tv.z, tv.w };
        const int   ss[4] = { sv.x, sv.y, sv.z, sv.w };
#pragma unroll
        for (int e = 0; e < 4; ++e) {
            const float p = xs[e] * ts[e];
#pragma unroll
            for (int k = 0; k < NB; ++k) {           // static indices -> VGPRs
                const float m = (ss[e] == k + 1) ? 1.0f : 0.0f;
                aI[k] = fmaf(m, p,     aI[k]);
                aX[k] = fmaf(m, xs[e], aX[k]);
                aT[k] = fmaf(m, ts[e], aT[k]);
                aC[k] += m;
            }
        }
    }

    // wave-64 butterfly reduction of all 40 partials
#pragma unroll
    for (int k = 0; k < NB; ++k) {
#pragma unroll
        for (int off = 32; off > 0; off >>= 1) {
            aI[k] += __shfl_down(aI[k], off);
            aX[k] += __shfl_down(aX[k], off);
            aT[k] += __shfl_down(aT[k], off);
            aC[k] += __shfl_down(aC[k], off);
        }
    }

    if ((threadIdx.x & 63) == 0) {
        float* accI = acc;
        float* accX = acc + BATCH * NB;
        float* accT = acc + 2 * BATCH * NB;
        float* accC = acc + 3 * BATCH * NB;
#pragma unroll
        for (int k = 0; k < NB; ++k) {
            atomicAdd(&accI[batch * NB + k], aI[k]);
            atomicAdd(&accX[batch * NB + k], aX[k]);
            atomicAdd(&accT[batch * NB + k], aT[k]);
            atomicAdd(&accC[k], aC[k]);
        }
    }
}

__global__ void dice_final(const float* __restrict__ acc, float* __restrict__ out)
{
    const int k = threadIdx.x;
    float lpb = 0.0f, pres = 0.0f;
    if (k < NB) {
        const float* accI = acc;
        const float* accX = acc + BATCH * NB;
        const float* accT = acc + 2 * BATCH * NB;
        const float* accC = acc + 3 * BATCH * NB;
        float sum_loss = 0.0f, valid = 0.0f;
        for (int b = 0; b < BATCH; ++b) {
            const float I = accI[b * NB + k];
            const float X = accX[b * NB + k];
            const float T = accT[b * NB + k];
            const float denom = X + T + 2.0f * EPSF;
            float bl = 1.0f - 2.0f * I / denom;
            if (T == 0.0f) bl = 0.0f; else valid += 1.0f;
            sum_loss += bl;
        }
        lpb  = sum_loss / fmaxf(valid, 1.0f);
        pres = (accC[k] > 0.0f) ? 1.0f : 0.0f;
    }
    float num = pres;
    float ls  = (pres > 0.0f) ? lpb : 0.0f;
    for (int off = 32; off > 0; off >>= 1) {
        num += __shfl_down(num, off);
        ls  += __shfl_down(ls,  off);
    }
    if (threadIdx.x == 0) {
        out[0] = ls / num;   // num>0 for this data; 0/0 -> nan matches ref
        out[1] = 0.0f;       // second tuple element (int 0 == float 0 bitwise)
    }
}

extern "C" void kernel_launch(void* const* d_in, const int* in_sizes, int n_in,
                              void* d_out, int out_size, void* d_ws, size_t ws_size,
                              hipStream_t stream)
{
    const float* x = (const float*)d_in[0];
    const float* t = (const float*)d_in[1];
    const int*   s = (const int*)d_in[2];
    float* out = (float*)d_out;
    float* acc = (float*)d_ws;

    hipMemsetAsync(acc, 0, WS_FLOATS * sizeof(float), stream);

    dim3 grid(BLOCKS_PER_BATCH, BATCH);
    dice_partial<<<grid, THREADS, 0, stream>>>(x, t, s, acc);
    dice_final<<<1, 64, 0, stream>>>(acc, out);
}

// Round 2
// 296.692 us; speedup vs baseline: 3.7922x; 3.7922x over previous
//
#include <hip/hip_runtime.h>

#define NB 10   // labels 1..10
#define BATCH 8
#define EPSF 1e-6f

constexpr int ELEMS_PER_BATCH = 128 * 128 * 128;        // 2,097,152
constexpr int VEC_PER_BATCH   = ELEMS_PER_BATCH / 4;    // 524,288 float4
constexpr int THREADS         = 256;
constexpr int VPT             = 8;                      // float4 loads per thread
constexpr int BLOCKS_PER_BATCH = VEC_PER_BATCH / (THREADS * VPT); // 256

// LDS histogram: bins 0..10 for I, 11..21 for X, 22..32 for T (bin = which*11 + label)
constexpr int NBINS = 33;

// ws layout (floats): accI[BATCH][NB], accX[BATCH][NB], accT[BATCH][NB], mask (int) at [240]
constexpr int WS_FLOATS = 3 * BATCH * NB + 1;

__global__ __launch_bounds__(THREADS)
void dice_partial(const float* __restrict__ x,
                  const float* __restrict__ t,
                  const int*   __restrict__ s,
                  float* __restrict__ acc)
{
    __shared__ float hist[NBINS][THREADS];

    const int tid = threadIdx.x;
    const int batch = blockIdx.y;
    const long long base = (long long)batch * VEC_PER_BATCH
                         + (long long)blockIdx.x * (THREADS * VPT);
    const float4* x4 = reinterpret_cast<const float4*>(x) + base;
    const float4* t4 = reinterpret_cast<const float4*>(t) + base;
    const int4*   s4 = reinterpret_cast<const int4*>(s)   + base;

#pragma unroll
    for (int b = 0; b < NBINS; ++b) hist[b][tid] = 0.0f;
    __syncthreads();

    unsigned bits = 0;                 // bit k set <=> label value k seen (k=0..10)
    float* col = &hist[0][tid];        // column base; bin b is col[b*THREADS]

#pragma unroll
    for (int i = 0; i < VPT; ++i) {
        const int idx = i * THREADS + tid;           // coalesced
        const float4 xv = x4[idx];
        const float4 tv = t4[idx];
        const int4   sv = s4[idx];
        const float xs[4] = { xv.x, xv.y, xv.z, xv.w };
        const float ts[4] = { tv.x, tv.y, tv.z, tv.w };
        const int   ss[4] = { sv.x, sv.y, sv.z, sv.w };
#pragma unroll
        for (int e = 0; e < 4; ++e) {
            const int lbl = ss[e];                   // 0..10
            bits |= (1u << lbl);
            const float p = xs[e] * ts[e];
            // [bin][tid] layout: bank = tid%32 regardless of lbl -> conflict-free
            atomicAdd(&col[lbl * THREADS], p);                        // ds_add_f32
            atomicAdd(&col[(11 + lbl) * THREADS], xs[e]);
            atomicAdd(&col[(22 + lbl) * THREADS], ts[e]);
        }
    }

    // presence: wave OR-reduce, then one atomicOr per wave
#pragma unroll
    for (int off = 32; off > 0; off >>= 1)
        bits |= (unsigned)__shfl_xor((int)bits, off);
    if ((tid & 63) == 0)
        atomicOr((unsigned*)(acc + 3 * BATCH * NB), bits >> 1);  // bits for labels 1..10

    __syncthreads();

    // tree-reduce each bin's 256 partials
    for (int st = THREADS / 2; st > 0; st >>= 1) {
        if (tid < st) {
#pragma unroll
            for (int b = 0; b < NBINS; ++b)
                hist[b][tid] += hist[b][tid + st];
        }
        __syncthreads();
    }

    // 30 useful sums: which = 0(I),1(X),2(T); label 1..10 -> bin which*11 + label
    if (tid < 30) {
        const int which = tid / NB;          // 0,1,2
        const int lab   = tid % NB;          // 0..9 for labels 1..10
        const float v = hist[which * 11 + (lab + 1)][0];
        atomicAdd(&acc[which * BATCH * NB + batch * NB + lab], v);
    }
}

__global__ void dice_final(const float* __restrict__ acc, float* __restrict__ out)
{
    const int k = threadIdx.x;
    const unsigned mask = *(const unsigned*)(acc + 3 * BATCH * NB);
    float lpb = 0.0f, pres = 0.0f;
    if (k < NB) {
        const float* accI = acc;
        const float* accX = acc + BATCH * NB;
        const float* accT = acc + 2 * BATCH * NB;
        float sum_loss = 0.0f, valid = 0.0f;
        for (int b = 0; b < BATCH; ++b) {
            const float I = accI[b * NB + k];
            const float X = accX[b * NB + k];
            const float T = accT[b * NB + k];
            const float denom = X + T + 2.0f * EPSF;
            float bl = 1.0f - 2.0f * I / denom;
            if (T == 0.0f) bl = 0.0f; else valid += 1.0f;
            sum_loss += bl;
        }
        lpb  = sum_loss / fmaxf(valid, 1.0f);
        pres = ((mask >> k) & 1u) ? 1.0f : 0.0f;
    }
    float num = pres;
    float ls  = (pres > 0.0f) ? lpb : 0.0f;
    for (int off = 32; off > 0; off >>= 1) {
        num += __shfl_down(num, off);
        ls  += __shfl_down(ls,  off);
    }
    if (threadIdx.x == 0) {
        out[0] = ls / num;
        out[1] = 0.0f;
    }
}

extern "C" void kernel_launch(void* const* d_in, const int* in_sizes, int n_in,
                              void* d_out, int out_size, void* d_ws, size_t ws_size,
                              hipStream_t stream)
{
    const float* x = (const float*)d_in[0];
    const float* t = (const float*)d_in[1];
    const int*   s = (const int*)d_in[2];
    float* out = (float*)d_out;
    float* acc = (float*)d_ws;

    hipMemsetAsync(acc, 0, WS_FLOATS * sizeof(float), stream);

    dim3 grid(BLOCKS_PER_BATCH, BATCH);
    dice_partial<<<grid, THREADS, 0, stream>>>(x, t, s, acc);
    dice_final<<<1, 64, 0, stream>>>(acc, out);
}

// Round 3
// 60.874 us; speedup vs baseline: 18.4830x; 4.8739x over previous
//
#include <hip/hip_runtime.h>

#define NB 10   // labels 1..10
#define BATCH 8
#define EPSF 1e-6f

constexpr int ELEMS_PER_BATCH = 128 * 128 * 128;        // 2,097,152
constexpr int VEC_PER_BATCH   = ELEMS_PER_BATCH / 4;    // 524,288 float4
constexpr int THREADS         = 256;
constexpr int VPT             = 8;                      // float4 loads per thread
constexpr int BLOCKS_PER_BATCH = VEC_PER_BATCH / (THREADS * VPT); // 256

// ws layout: accI[8][10], accX[8][10], accT[8][10] floats, then 8 uint presence masks
constexpr int WS_FLOATS = 3 * BATCH * NB;   // 240
constexpr int WS_BYTES  = WS_FLOATS * 4 + BATCH * 4;

__global__ __launch_bounds__(THREADS, 1)   // min 1 wave/EU: lift VGPR cap, avoid spill
void dice_partial(const float* __restrict__ x,
                  const float* __restrict__ t,
                  const int*   __restrict__ s,
                  float* __restrict__ acc)
{
    const int tid   = threadIdx.x;
    const int batch = blockIdx.y;
    const long long base = (long long)batch * VEC_PER_BATCH
                         + (long long)blockIdx.x * (THREADS * VPT);
    const float4* x4 = reinterpret_cast<const float4*>(x) + base;
    const float4* t4 = reinterpret_cast<const float4*>(t) + base;
    const int4*   s4 = reinterpret_cast<const int4*>(s)   + base;

    float aI[NB], aX[NB], aT[NB];
#pragma unroll
    for (int k = 0; k < NB; ++k) { aI[k] = 0.f; aX[k] = 0.f; aT[k] = 0.f; }
    unsigned bits = 0;   // bit v set <=> label value v seen

#define DO_ELEM(xe, te, se)                                     \
    do {                                                        \
        const float _x = (xe), _t = (te);                       \
        const int   _s = (se);                                  \
        const float _p = _x * _t;                               \
        bits |= (1u << _s);                                     \
        _Pragma("unroll")                                       \
        for (int k = 0; k < NB; ++k) {                          \
            const float m = (_s == k + 1) ? 1.0f : 0.0f;        \
            aI[k] = fmaf(m, _p, aI[k]);                         \
            aX[k] = fmaf(m, _x, aX[k]);                         \
            aT[k] = fmaf(m, _t, aT[k]);                         \
        }                                                       \
    } while (0)

#pragma unroll
    for (int i = 0; i < VPT; ++i) {
        const int idx = i * THREADS + tid;          // coalesced, 16B/lane
        const float4 xv = x4[idx];
        const float4 tv = t4[idx];
        const int4   sv = s4[idx];
        DO_ELEM(xv.x, tv.x, sv.x);
        DO_ELEM(xv.y, tv.y, sv.y);
        DO_ELEM(xv.z, tv.z, sv.z);
        DO_ELEM(xv.w, tv.w, sv.w);
    }
#undef DO_ELEM

    // wave-64 butterfly: every lane ends with the wave sum
#pragma unroll
    for (int k = 0; k < NB; ++k) {
#pragma unroll
        for (int off = 32; off > 0; off >>= 1) {
            aI[k] += __shfl_xor(aI[k], off);
            aX[k] += __shfl_xor(aX[k], off);
            aT[k] += __shfl_xor(aT[k], off);
        }
    }
#pragma unroll
    for (int off = 32; off > 0; off >>= 1)
        bits |= (unsigned)__shfl_xor((int)bits, off);

    // cross-wave combine in LDS (4 waves), then ~31 global atomics per block
    __shared__ float    wsum[4][32];
    __shared__ unsigned wb[4];
    const int wave = tid >> 6, lane = tid & 63;
    if (lane < NB) {
        wsum[wave][lane]          = aI[lane];
        wsum[wave][NB + lane]     = aX[lane];
        wsum[wave][2 * NB + lane] = aT[lane];
    }
    if (lane == 0) wb[wave] = bits;
    __syncthreads();

    if (tid < 3 * NB) {
        const float v = wsum[0][tid] + wsum[1][tid] + wsum[2][tid] + wsum[3][tid];
        const int which = tid / NB;          // 0:I 1:X 2:T
        const int lab   = tid % NB;
        atomicAdd(&acc[which * BATCH * NB + batch * NB + lab], v);
    }
    if (tid == 0) {
        const unsigned m = (wb[0] | wb[1] | wb[2] | wb[3]) >> 1;  // labels 1..10
        atomicOr((unsigned*)(acc + WS_FLOATS) + batch, m);
    }
}

__global__ void dice_final(const float* __restrict__ acc, float* __restrict__ out)
{
    const unsigned* pm = (const unsigned*)(acc + WS_FLOATS);
    unsigned mask = 0;
#pragma unroll
    for (int b = 0; b < BATCH; ++b) mask |= pm[b];

    const int k = threadIdx.x;
    float lpb = 0.0f, pres = 0.0f;
    if (k < NB) {
        const float* accI = acc;
        const float* accX = acc + BATCH * NB;
        const float* accT = acc + 2 * BATCH * NB;
        float sum_loss = 0.0f, valid = 0.0f;
        for (int b = 0; b < BATCH; ++b) {
            const float I = accI[b * NB + k];
            const float X = accX[b * NB + k];
            const float T = accT[b * NB + k];
            const float denom = X + T + 2.0f * EPSF;
            float bl = 1.0f - 2.0f * I / denom;
            if (T == 0.0f) bl = 0.0f; else valid += 1.0f;
            sum_loss += bl;
        }
        lpb  = sum_loss / fmaxf(valid, 1.0f);
        pres = ((mask >> k) & 1u) ? 1.0f : 0.0f;
    }
    float num = pres;
    float ls  = (pres > 0.0f) ? lpb : 0.0f;
    for (int off = 32; off > 0; off >>= 1) {
        num += __shfl_down(num, off);
        ls  += __shfl_down(ls,  off);
    }
    if (threadIdx.x == 0) {
        out[0] = ls / num;
        out[1] = 0.0f;
    }
}

extern "C" void kernel_launch(void* const* d_in, const int* in_sizes, int n_in,
                              void* d_out, int out_size, void* d_ws, size_t ws_size,
                              hipStream_t stream)
{
    const float* x = (const float*)d_in[0];
    const float* t = (const float*)d_in[1];
    const int*   s = (const int*)d_in[2];
    float* out = (float*)d_out;
    float* acc = (float*)d_ws;

    hipMemsetAsync(acc, 0, WS_BYTES, stream);

    dim3 grid(BLOCKS_PER_BATCH, BATCH);
    dice_partial<<<grid, THREADS, 0, stream>>>(x, t, s, acc);
    dice_final<<<1, 64, 0, stream>>>(acc, out);
}